// Round 5
// baseline (835.589 us; speedup 1.0000x reference)
//
#include <hip/hip_runtime.h>
#include <hip/hip_bf16.h>

// GRU, 16 steps, B=4096, H=1024. x==h for steps>=1 -> combined gate weights.
// Gate GEMM (fused): Z = h_bf16 @ Wc'[4H,H]^T, gate-interleaved; GRU epilogue
//   in-register. Out GEMM batched over all 16 steps.
// GEMM core: 256x256 tile, 8 waves, m201-style 8-phase schedule:
//   unit = K-slice of 32 (A+B, 32 KiB), 4 LDS slots, staged 3 units ahead,
//   2 double-barriered phases/unit, 16 MFMA each, counted vmcnt(8) (never 0
//   in steady state), explicit lgkmcnt(0)+sched_barrier after each barrier,
//   setprio around MFMA clusters, both-sides XOR swizzle (0 bank conflicts).

#define H_DIM 1024
#define BATCH_N 4096
#define NSTEPS 16
#define K4 (4 * H_DIM)

typedef __bf16 bf16_t;
typedef __bf16 bf16x8 __attribute__((ext_vector_type(8)));
typedef float f32x4 __attribute__((ext_vector_type(4)));

__device__ __forceinline__ float sigm(float x) { return 1.0f / (1.0f + __expf(-x)); }

// ---------------- prep kernels ----------------
// Wc' row c' (0..4095): gate g=(c'>>4)&3, h-row hc=((c'>>6)<<4)|(c'&15)
//   g: 0=r (Wih+Whh), 1=z (Wih+Whh), 2=i_n (Wih), 3=h_n (Whh)

__global__ __launch_bounds__(256) void prep_weights(
    const float* __restrict__ Wih, const float* __restrict__ Whh,
    const float* __restrict__ bih, const float* __restrict__ bhh,
    const float* __restrict__ Wout,
    bf16_t* __restrict__ Wc0, bf16_t* __restrict__ Wc,
    bf16_t* __restrict__ Wob, float* __restrict__ biasc)
{
    const int stride = gridDim.x * blockDim.x;
    const int idx = blockIdx.x * blockDim.x + threadIdx.x;

    const int total = K4 * H_DIM;
    for (int i = idx; i < total; i += stride) {
        const int c2 = i >> 10;            // permuted row
        const int col = i & (H_DIM - 1);
        const int gate = (c2 >> 4) & 3;
        const int hc = ((c2 >> 6) << 4) | (c2 & 15);
        float vc, v0;
        if (gate == 0) {
            float a = Wih[(size_t)hc * H_DIM + col];
            float b = Whh[(size_t)hc * H_DIM + col];
            vc = a + b; v0 = b;
        } else if (gate == 1) {
            float a = Wih[(size_t)(H_DIM + hc) * H_DIM + col];
            float b = Whh[(size_t)(H_DIM + hc) * H_DIM + col];
            vc = a + b; v0 = b;
        } else if (gate == 2) {
            vc = Wih[(size_t)(2 * H_DIM + hc) * H_DIM + col];
            v0 = 0.0f;   // step 0: x = 0
        } else {
            float b = Whh[(size_t)(2 * H_DIM + hc) * H_DIM + col];
            vc = b; v0 = b;
        }
        Wc[i]  = (bf16_t)vc;
        Wc0[i] = (bf16_t)v0;
    }
    for (int i = idx; i < H_DIM * H_DIM; i += stride)
        Wob[i] = (bf16_t)Wout[i];
    // biasc gate-major [4][H]
    for (int i = idx; i < K4; i += stride) {
        const int gate = i >> 10;
        const int hc = i & (H_DIM - 1);
        float v;
        if (gate == 0)      v = bih[hc] + bhh[hc];
        else if (gate == 1) v = bih[H_DIM + hc] + bhh[H_DIM + hc];
        else if (gate == 2) v = bih[2 * H_DIM + hc];
        else                v = bhh[2 * H_DIM + hc];
        biasc[i] = v;
    }
}

__global__ __launch_bounds__(256) void prep_h(
    const float* __restrict__ h0, bf16_t* __restrict__ hb)
{
    const int stride = gridDim.x * blockDim.x;
    for (int i = blockIdx.x * blockDim.x + threadIdx.x; i < BATCH_N * H_DIM; i += stride)
        hb[i] = (bf16_t)h0[i];
}

// ---------------- 256x256 8-phase GEMM ----------------
// C[M,N] = A[M,K] @ Bm[N,K]^T. 8 waves: wr=w>>2 (2), wc=w&3 (4).
// Wave output 128x64, acc[8][4].
// Unit z = K-cols [32z, 32z+32): slot z&3 holds A[256][32] (+0) and
// B[256][32] (+8192 elems). Swizzle (involution, verified 0 conflicts):
//   LDS[row][slot_p] = G[row][slot_p ^ ((row>>1)&3)] (16B slots)
//   stage: linear LDS dest, pre-swizzled global col; read: XOR'd col.

__device__ __forceinline__ void stage_half(
    const bf16_t* __restrict__ g, int grow0, int K, int k0,
    bf16_t* ldsbase, int l)
{
    const int colsrc = (((l & 3) ^ ((l >> 3) & 3)) << 3);
    const bf16_t* ga = g + (size_t)(grow0 + (l >> 2)) * K + k0 + colsrc;
    __builtin_amdgcn_global_load_lds(
        (const __attribute__((address_space(1))) void*)ga,
        (__attribute__((address_space(3))) void*)ldsbase, 16, 0, 0);
}

template <bool FUSED>
__global__ __launch_bounds__(512, 2) void gemm256(
    const bf16_t* __restrict__ A, const bf16_t* __restrict__ Bm,
    int M, int N, int K,
    float* __restrict__ C, const float* __restrict__ bias,
    const float* __restrict__ biasc,
    bf16_t* __restrict__ hbout, bf16_t* __restrict__ hr)
{
    __shared__ bf16_t lds[65536];   // 4 slots x (A 16KiB + B 16KiB) = 128 KiB

    const int tid = threadIdx.x;
    const int l = tid & 63;
    const int w = tid >> 6;         // 0..7
    const int wr = w >> 2;          // 0..1
    const int wc = w & 3;           // 0..3

    // block swizzle
    int bx, by;
    if constexpr (FUSED) {
        // 16x16 grid -> 8 XCD regions of 4(bx) x 8(by)
        const int d = blockIdx.x;
        const int r = d & 7, s = d >> 3;
        bx = (r & 3) * 4 + (s & 3);
        by = (r >> 2) * 8 + (s >> 2);
    } else {
        const int nbx = N >> 8;
        const int cpx = gridDim.x >> 3;
        const int d = blockIdx.x;
        const int bid = (d & 7) * cpx + (d >> 3);
        bx = bid % nbx;
        by = bid / nbx;
    }
    const int brow = by * 256;
    const int bcol = bx * 256;

    f32x4 acc[8][4];
    const f32x4 zero = {0.f, 0.f, 0.f, 0.f};
#pragma unroll
    for (int m = 0; m < 8; ++m)
#pragma unroll
        for (int n = 0; n < 4; ++n) acc[m][n] = zero;

    const int Z = K >> 5;   // units of K=32

#define STAGE_A(zz) do { \
    bf16_t* lb_ = lds + ((zz) & 3) * 16384 + w * 512; \
    stage_half(A, brow + w * 16, K, (zz) * 32, lb_, l); \
    stage_half(A, brow + 128 + w * 16, K, (zz) * 32, lb_ + 4096, l); \
} while (0)
#define STAGE_B(zz) do { \
    bf16_t* lb_ = lds + ((zz) & 3) * 16384 + 8192 + w * 512; \
    stage_half(Bm, bcol + w * 16, K, (zz) * 32, lb_, l); \
    stage_half(Bm, bcol + 128 + w * 16, K, (zz) * 32, lb_ + 4096, l); \
} while (0)

    // prologue: stage units 0,1,2 (12 loads/thread), make unit 0 resident
    STAGE_A(0); STAGE_B(0);
    STAGE_A(1); STAGE_B(1);
    STAGE_A(2); STAGE_B(2);
    asm volatile("s_waitcnt vmcnt(8)" ::: "memory");
    __builtin_amdgcn_s_barrier();

    const int colrd = (((l >> 4) ^ ((l >> 1) & 3)) << 3);
    const int ar0 = (wr * 128 + (l & 15)) * 32 + colrd;
    const int br0 = 8192 + (wc * 64 + (l & 15)) * 32 + colrd;

    bf16x8 afrag[4], bfrag[4];
    for (int z = 0; z < Z; ++z) {
        const int sb = (z & 3) * 16384;

        // ---- phase 0: read B + A[m0-3]; stage A(z+3); 16 MFMA ----
#pragma unroll
        for (int n = 0; n < 4; ++n)
            bfrag[n] = *(const bf16x8*)&lds[sb + br0 + n * 512];
#pragma unroll
        for (int m = 0; m < 4; ++m)
            afrag[m] = *(const bf16x8*)&lds[sb + ar0 + m * 512];
        if (z + 3 < Z) STAGE_A(z + 3);
        __builtin_amdgcn_s_barrier();
        asm volatile("s_waitcnt lgkmcnt(0)" ::: "memory");
        __builtin_amdgcn_sched_barrier(0);
        __builtin_amdgcn_s_setprio(1);
#pragma unroll
        for (int m = 0; m < 4; ++m)
#pragma unroll
            for (int n = 0; n < 4; ++n)
                acc[m][n] = __builtin_amdgcn_mfma_f32_16x16x32_bf16(afrag[m], bfrag[n], acc[m][n], 0, 0, 0);
        __builtin_amdgcn_s_setprio(0);
        __builtin_amdgcn_s_barrier();

        // ---- phase 1: read A[m4-7]; stage B(z+3); vmcnt; 16 MFMA ----
#pragma unroll
        for (int m = 0; m < 4; ++m)
            afrag[m] = *(const bf16x8*)&lds[sb + ar0 + (m + 4) * 512];
        if (z + 3 < Z) STAGE_B(z + 3);
        if (z < Z - 3)       asm volatile("s_waitcnt vmcnt(8)" ::: "memory");
        else if (z == Z - 3) asm volatile("s_waitcnt vmcnt(4)" ::: "memory");
        else                 asm volatile("s_waitcnt vmcnt(0)" ::: "memory");
        __builtin_amdgcn_s_barrier();
        asm volatile("s_waitcnt lgkmcnt(0)" ::: "memory");
        __builtin_amdgcn_sched_barrier(0);
        __builtin_amdgcn_s_setprio(1);
#pragma unroll
        for (int m = 0; m < 4; ++m)
#pragma unroll
            for (int n = 0; n < 4; ++n)
                acc[m + 4][n] = __builtin_amdgcn_mfma_f32_16x16x32_bf16(afrag[m], bfrag[n], acc[m + 4][n], 0, 0, 0);
        __builtin_amdgcn_s_setprio(0);
        __builtin_amdgcn_s_barrier();
    }
#undef STAGE_A
#undef STAGE_B

    // C/D layout: col = lane&15, row = (lane>>4)*4 + j  [verified m89/m91]
    if constexpr (FUSED) {
        // fragment n = gate n of h-col hc
        const int hc = (bx * 4 + wc) * 16 + (l & 15);
        const float br_ = biasc[hc];
        const float bz_ = biasc[H_DIM + hc];
        const float bi_ = biasc[2 * H_DIM + hc];
        const float bh_ = biasc[3 * H_DIM + hc];
        const int r0 = brow + wr * 128 + ((l >> 4) << 2);
#pragma unroll
        for (int m = 0; m < 8; ++m) {
#pragma unroll
            for (int j = 0; j < 4; ++j) {
                const int row = r0 + m * 16 + j;
                const size_t o = (size_t)row * H_DIM + hc;
                const float hold = (float)A[o];   // h_old (read-only this launch)
                const float r = sigm(acc[m][0][j] + br_);
                const float z = sigm(acc[m][1][j] + bz_);
                float a = acc[m][2][j] + bi_ + r * (acc[m][3][j] + bh_);
                a = fminf(fmaxf(a, -30.f), 30.f);
                const float e = __expf(-2.f * a);
                const float nn = (1.f - e) / (1.f + e);
                const float hn = (1.f - z) * nn + z * hold;
                hbout[o] = (bf16_t)hn;
                hr[o] = (bf16_t)fmaxf(hn, 0.f);
            }
        }
    } else {
        const int r0 = brow + wr * 128 + ((l >> 4) << 2);
        const int c0 = bcol + wc * 64 + (l & 15);
#pragma unroll
        for (int m = 0; m < 8; ++m) {
#pragma unroll
            for (int n = 0; n < 4; ++n) {
                const int col = c0 + n * 16;
                const float badd = bias ? bias[col] : 0.0f;
#pragma unroll
                for (int j = 0; j < 4; ++j) {
                    const int row = r0 + m * 16 + j;
                    C[(size_t)row * N + col] = acc[m][n][j] + badd;
                }
            }
        }
    }
}

// ---------------- launch ----------------

extern "C" void kernel_launch(void* const* d_in, const int* in_sizes, int n_in,
                              void* d_out, int out_size, void* d_ws, size_t ws_size,
                              hipStream_t stream)
{
    const float* hidden = (const float*)d_in[0];
    const float* Wih = (const float*)d_in[1];
    const float* Whh = (const float*)d_in[2];
    const float* bih = (const float*)d_in[3];
    const float* bhh = (const float*)d_in[4];
    const float* Wout = (const float*)d_in[5];
    const float* bout = (const float*)d_in[6];
    float* out = (float*)d_out;
    (void)in_sizes; (void)n_in; (void)out_size;

    char* ws = (char*)d_ws;
    size_t off = 0;
    bf16_t* Wc0 = (bf16_t*)(ws + off); off += (size_t)K4 * H_DIM * 2;        // 8 MB
    bf16_t* Wc  = (bf16_t*)(ws + off); off += (size_t)K4 * H_DIM * 2;        // 8 MB
    bf16_t* Wob = (bf16_t*)(ws + off); off += (size_t)H_DIM * H_DIM * 2;     // 2 MB
    float*  biasc = (float*)(ws + off); off += (size_t)K4 * 4;               // 16 KB
    bf16_t* hbA = (bf16_t*)(ws + off); off += (size_t)BATCH_N * H_DIM * 2;   // 8 MB
    bf16_t* hbB = (bf16_t*)(ws + off); off += (size_t)BATCH_N * H_DIM * 2;   // 8 MB

    const size_t hr_step = (size_t)BATCH_N * H_DIM;
    const size_t need_batched = off + NSTEPS * hr_step * 2;
    const bool batched = (ws_size >= need_batched);
    bf16_t* hr_all = (bf16_t*)(ws + off);               // 128 MB if batched

    prep_weights<<<1024, 256, 0, stream>>>(Wih, Whh, bih, bhh, Wout, Wc0, Wc, Wob, biasc);
    prep_h<<<2048, 256, 0, stream>>>(hidden, hbA);

    for (int t = 0; t < NSTEPS; ++t) {
        bf16_t* hin  = (t & 1) ? hbB : hbA;
        bf16_t* hout = (t & 1) ? hbA : hbB;
        bf16_t* hr_t = batched ? (hr_all + (size_t)t * hr_step) : hr_all;
        // fused gate GEMM: M=4096, N=4096, K=1024 + GRU epilogue (16x16 grid)
        gemm256<true><<<(BATCH_N / 256) * (K4 / 256), 512, 0, stream>>>(
            hin, (t == 0) ? Wc0 : Wc, BATCH_N, K4, H_DIM,
            nullptr, nullptr, biasc, hout, hr_t);
        if (!batched) {
            gemm256<false><<<(BATCH_N / 256) * (H_DIM / 256), 512, 0, stream>>>(
                hr_t, Wob, BATCH_N, H_DIM, H_DIM,
                out + (size_t)t * hr_step, bout, nullptr, nullptr, nullptr);
        }
    }
    if (batched) {
        // one big out GEMM: M = 16*4096, N = 1024, K = 1024
        gemm256<false><<<((NSTEPS * BATCH_N) / 256) * (H_DIM / 256), 512, 0, stream>>>(
            hr_all, Wob, NSTEPS * BATCH_N, H_DIM, H_DIM,
            out, bout, nullptr, nullptr, nullptr);
    }
}

// Round 6
// 768.893 us; speedup vs baseline: 1.0867x; 1.0867x over previous
//
#include <hip/hip_runtime.h>
#include <hip/hip_bf16.h>

// GRU, 16 steps, B=4096, H=1024. x==h for steps>=1 -> combined gate weights.
// Gate GEMM (fused): Z = h_bf16 @ Wc'[4H,H]^T, gate-interleaved; GRU epilogue
//   in-register. Out GEMM batched over all 16 steps.
// GEMM core: 256x256 tile, 8 waves, BK=32 units, 4 LDS slots, distance-3
//   prefetch, counted vmcnt (8/4/0 tail), ONE barrier per unit, unpinned
//   interior (compiler lgkmcnt; waves desync -> LDS reads overlap MFMA),
//   setprio around MFMA clusters, both-sides XOR swizzle (0 bank conflicts).

#define H_DIM 1024
#define BATCH_N 4096
#define NSTEPS 16
#define K4 (4 * H_DIM)

typedef __bf16 bf16_t;
typedef __bf16 bf16x8 __attribute__((ext_vector_type(8)));
typedef float f32x4 __attribute__((ext_vector_type(4)));

__device__ __forceinline__ float sigm(float x) { return 1.0f / (1.0f + __expf(-x)); }

// ---------------- prep kernels ----------------
// Wc' row c' (0..4095): gate g=(c'>>4)&3, h-row hc=((c'>>6)<<4)|(c'&15)
//   g: 0=r (Wih+Whh), 1=z (Wih+Whh), 2=i_n (Wih), 3=h_n (Whh)

__global__ __launch_bounds__(256) void prep_weights(
    const float* __restrict__ Wih, const float* __restrict__ Whh,
    const float* __restrict__ bih, const float* __restrict__ bhh,
    const float* __restrict__ Wout,
    bf16_t* __restrict__ Wc0, bf16_t* __restrict__ Wc,
    bf16_t* __restrict__ Wob, float* __restrict__ biasc)
{
    const int stride = gridDim.x * blockDim.x;
    const int idx = blockIdx.x * blockDim.x + threadIdx.x;

    const int total = K4 * H_DIM;
    for (int i = idx; i < total; i += stride) {
        const int c2 = i >> 10;            // permuted row
        const int col = i & (H_DIM - 1);
        const int gate = (c2 >> 4) & 3;
        const int hc = ((c2 >> 6) << 4) | (c2 & 15);
        float vc, v0;
        if (gate == 0) {
            float a = Wih[(size_t)hc * H_DIM + col];
            float b = Whh[(size_t)hc * H_DIM + col];
            vc = a + b; v0 = b;
        } else if (gate == 1) {
            float a = Wih[(size_t)(H_DIM + hc) * H_DIM + col];
            float b = Whh[(size_t)(H_DIM + hc) * H_DIM + col];
            vc = a + b; v0 = b;
        } else if (gate == 2) {
            vc = Wih[(size_t)(2 * H_DIM + hc) * H_DIM + col];
            v0 = 0.0f;   // step 0: x = 0
        } else {
            float b = Whh[(size_t)(2 * H_DIM + hc) * H_DIM + col];
            vc = b; v0 = b;
        }
        Wc[i]  = (bf16_t)vc;
        Wc0[i] = (bf16_t)v0;
    }
    for (int i = idx; i < H_DIM * H_DIM; i += stride)
        Wob[i] = (bf16_t)Wout[i];
    // biasc gate-major [4][H]
    for (int i = idx; i < K4; i += stride) {
        const int gate = i >> 10;
        const int hc = i & (H_DIM - 1);
        float v;
        if (gate == 0)      v = bih[hc] + bhh[hc];
        else if (gate == 1) v = bih[H_DIM + hc] + bhh[H_DIM + hc];
        else if (gate == 2) v = bih[2 * H_DIM + hc];
        else                v = bhh[2 * H_DIM + hc];
        biasc[i] = v;
    }
}

__global__ __launch_bounds__(256) void prep_h(
    const float* __restrict__ h0, bf16_t* __restrict__ hb)
{
    const int stride = gridDim.x * blockDim.x;
    for (int i = blockIdx.x * blockDim.x + threadIdx.x; i < BATCH_N * H_DIM; i += stride)
        hb[i] = (bf16_t)h0[i];
}

// ---------------- 256x256 GEMM, 1-barrier-per-unit pipeline ----------------
// C[M,N] = A[M,K] @ Bm[N,K]^T. 8 waves: wr=w>>2 (2), wc=w&3 (4).
// Wave output 128x64, acc[8][4].
// Unit z = K-cols [32z,32z+32): slot z&3 holds A[256][32] (+0) and
// B[256][32] (+8192 elems). Swizzle (involution, verified 0 conflicts):
//   stage: linear LDS dest, pre-swizzled global col; read: XOR'd col.
// Hazards: slot WAR (stage (z+3)&3 vs unit z-1 readers) separated by the
// unit-z barrier; residency RAW by counted vmcnt at unit top.

__device__ __forceinline__ void stage_half(
    const bf16_t* __restrict__ g, int grow0, int K, int k0,
    bf16_t* ldsbase, int l)
{
    const int colsrc = (((l & 3) ^ ((l >> 3) & 3)) << 3);
    const bf16_t* ga = g + (size_t)(grow0 + (l >> 2)) * K + k0 + colsrc;
    __builtin_amdgcn_global_load_lds(
        (const __attribute__((address_space(1))) void*)ga,
        (__attribute__((address_space(3))) void*)ldsbase, 16, 0, 0);
}

template <bool FUSED>
__global__ __launch_bounds__(512, 2) void gemm256(
    const bf16_t* __restrict__ A, const bf16_t* __restrict__ Bm,
    int M, int N, int K,
    float* __restrict__ C, const float* __restrict__ bias,
    const float* __restrict__ biasc,
    bf16_t* __restrict__ hbout, bf16_t* __restrict__ hr)
{
    __shared__ bf16_t lds[65536];   // 4 slots x (A 16KiB + B 16KiB) = 128 KiB

    const int tid = threadIdx.x;
    const int l = tid & 63;
    const int w = tid >> 6;         // 0..7
    const int wr = w >> 2;          // 0..1
    const int wc = w & 3;           // 0..3

    // block swizzle
    int bx, by;
    if constexpr (FUSED) {
        // 16x16 grid -> 8 XCD regions of 4(bx) x 8(by)
        const int d = blockIdx.x;
        const int r = d & 7, s = d >> 3;
        bx = (r & 3) * 4 + (s & 3);
        by = (r >> 2) * 8 + (s >> 2);
    } else {
        const int nbx = N >> 8;
        const int cpx = gridDim.x >> 3;
        const int d = blockIdx.x;
        const int bid = (d & 7) * cpx + (d >> 3);
        bx = bid % nbx;
        by = bid / nbx;
    }
    const int brow = by * 256;
    const int bcol = bx * 256;

    f32x4 acc[8][4];
    const f32x4 zero = {0.f, 0.f, 0.f, 0.f};
#pragma unroll
    for (int m = 0; m < 8; ++m)
#pragma unroll
        for (int n = 0; n < 4; ++n) acc[m][n] = zero;

    const int Z = K >> 5;   // units of K=32

#define STAGE_A(zz) do { \
    bf16_t* lb_ = lds + ((zz) & 3) * 16384 + w * 512; \
    stage_half(A, brow + w * 16, K, (zz) * 32, lb_, l); \
    stage_half(A, brow + 128 + w * 16, K, (zz) * 32, lb_ + 4096, l); \
} while (0)
#define STAGE_B(zz) do { \
    bf16_t* lb_ = lds + ((zz) & 3) * 16384 + 8192 + w * 512; \
    stage_half(Bm, bcol + w * 16, K, (zz) * 32, lb_, l); \
    stage_half(Bm, bcol + 128 + w * 16, K, (zz) * 32, lb_ + 4096, l); \
} while (0)

    // prologue: stage units 0,1,2 (12 loads/thread)
    STAGE_A(0); STAGE_B(0);
    STAGE_A(1); STAGE_B(1);
    STAGE_A(2); STAGE_B(2);

    const int colrd = (((l >> 4) ^ ((l >> 1) & 3)) << 3);
    const int ar0 = (wr * 128 + (l & 15)) * 32 + colrd;
    const int br0 = 8192 + (wc * 64 + (l & 15)) * 32 + colrd;

    bf16x8 afrag[4], bfrag[4];
    for (int z = 0; z < Z; ++z) {
        // unit-top sync: unit z resident (counted vmcnt), slot WAR fence
        if (z + 2 < Z)      asm volatile("s_waitcnt vmcnt(8)" ::: "memory");
        else if (z + 1 < Z) asm volatile("s_waitcnt vmcnt(4)" ::: "memory");
        else                asm volatile("s_waitcnt vmcnt(0)" ::: "memory");
        __builtin_amdgcn_s_barrier();

        const int sb = (z & 3) * 16384;

        // reads for cluster 0 (B all n, A m0-3), then prefetch A(z+3)
#pragma unroll
        for (int n = 0; n < 4; ++n)
            bfrag[n] = *(const bf16x8*)&lds[sb + br0 + n * 512];
#pragma unroll
        for (int m = 0; m < 4; ++m)
            afrag[m] = *(const bf16x8*)&lds[sb + ar0 + m * 512];
        if (z + 3 < Z) STAGE_A(z + 3);

        __builtin_amdgcn_s_setprio(1);
#pragma unroll
        for (int m = 0; m < 4; ++m)
#pragma unroll
            for (int n = 0; n < 4; ++n)
                acc[m][n] = __builtin_amdgcn_mfma_f32_16x16x32_bf16(afrag[m], bfrag[n], acc[m][n], 0, 0, 0);
        __builtin_amdgcn_s_setprio(0);

        // reads for cluster 1 (A m4-7) can overlap cluster 0 MFMAs
        bf16x8 afrag2[4];
#pragma unroll
        for (int m = 0; m < 4; ++m)
            afrag2[m] = *(const bf16x8*)&lds[sb + ar0 + (m + 4) * 512];
        if (z + 3 < Z) STAGE_B(z + 3);

        __builtin_amdgcn_s_setprio(1);
#pragma unroll
        for (int m = 0; m < 4; ++m)
#pragma unroll
            for (int n = 0; n < 4; ++n)
                acc[m + 4][n] = __builtin_amdgcn_mfma_f32_16x16x32_bf16(afrag2[m], bfrag[n], acc[m + 4][n], 0, 0, 0);
        __builtin_amdgcn_s_setprio(0);
    }
#undef STAGE_A
#undef STAGE_B

    // C/D layout: col = lane&15, row = (lane>>4)*4 + j  [verified m89/m91]
    if constexpr (FUSED) {
        // fragment n = gate n of h-col hc
        const int hc = (bx * 4 + wc) * 16 + (l & 15);
        const float br_ = biasc[hc];
        const float bz_ = biasc[H_DIM + hc];
        const float bi_ = biasc[2 * H_DIM + hc];
        const float bh_ = biasc[3 * H_DIM + hc];
        const int r0 = brow + wr * 128 + ((l >> 4) << 2);
#pragma unroll
        for (int m = 0; m < 8; ++m) {
#pragma unroll
            for (int j = 0; j < 4; ++j) {
                const int row = r0 + m * 16 + j;
                const size_t o = (size_t)row * H_DIM + hc;
                const float hold = (float)A[o];   // h_old (read-only this launch)
                const float r = sigm(acc[m][0][j] + br_);
                const float z = sigm(acc[m][1][j] + bz_);
                float a = acc[m][2][j] + bi_ + r * (acc[m][3][j] + bh_);
                a = fminf(fmaxf(a, -30.f), 30.f);
                const float e = __expf(-2.f * a);
                const float nn = (1.f - e) / (1.f + e);
                const float hn = (1.f - z) * nn + z * hold;
                hbout[o] = (bf16_t)hn;
                hr[o] = (bf16_t)fmaxf(hn, 0.f);
            }
        }
    } else {
        const int r0 = brow + wr * 128 + ((l >> 4) << 2);
        const int c0 = bcol + wc * 64 + (l & 15);
#pragma unroll
        for (int m = 0; m < 8; ++m) {
#pragma unroll
            for (int n = 0; n < 4; ++n) {
                const int col = c0 + n * 16;
                const float badd = bias ? bias[col] : 0.0f;
#pragma unroll
                for (int j = 0; j < 4; ++j) {
                    const int row = r0 + m * 16 + j;
                    C[(size_t)row * N + col] = acc[m][n][j] + badd;
                }
            }
        }
    }
}

// ---------------- launch ----------------

extern "C" void kernel_launch(void* const* d_in, const int* in_sizes, int n_in,
                              void* d_out, int out_size, void* d_ws, size_t ws_size,
                              hipStream_t stream)
{
    const float* hidden = (const float*)d_in[0];
    const float* Wih = (const float*)d_in[1];
    const float* Whh = (const float*)d_in[2];
    const float* bih = (const float*)d_in[3];
    const float* bhh = (const float*)d_in[4];
    const float* Wout = (const float*)d_in[5];
    const float* bout = (const float*)d_in[6];
    float* out = (float*)d_out;
    (void)in_sizes; (void)n_in; (void)out_size;

    char* ws = (char*)d_ws;
    size_t off = 0;
    bf16_t* Wc0 = (bf16_t*)(ws + off); off += (size_t)K4 * H_DIM * 2;        // 8 MB
    bf16_t* Wc  = (bf16_t*)(ws + off); off += (size_t)K4 * H_DIM * 2;        // 8 MB
    bf16_t* Wob = (bf16_t*)(ws + off); off += (size_t)H_DIM * H_DIM * 2;     // 2 MB
    float*  biasc = (float*)(ws + off); off += (size_t)K4 * 4;               // 16 KB
    bf16_t* hbA = (bf16_t*)(ws + off); off += (size_t)BATCH_N * H_DIM * 2;   // 8 MB
    bf16_t* hbB = (bf16_t*)(ws + off); off += (size_t)BATCH_N * H_DIM * 2;   // 8 MB

    const size_t hr_step = (size_t)BATCH_N * H_DIM;
    const size_t need_batched = off + NSTEPS * hr_step * 2;
    const bool batched = (ws_size >= need_batched);
    bf16_t* hr_all = (bf16_t*)(ws + off);               // 128 MB if batched

    prep_weights<<<1024, 256, 0, stream>>>(Wih, Whh, bih, bhh, Wout, Wc0, Wc, Wob, biasc);
    prep_h<<<2048, 256, 0, stream>>>(hidden, hbA);

    for (int t = 0; t < NSTEPS; ++t) {
        bf16_t* hin  = (t & 1) ? hbB : hbA;
        bf16_t* hout = (t & 1) ? hbA : hbB;
        bf16_t* hr_t = batched ? (hr_all + (size_t)t * hr_step) : hr_all;
        // fused gate GEMM: M=4096, N=4096, K=1024 + GRU epilogue (16x16 grid)
        gemm256<true><<<(BATCH_N / 256) * (K4 / 256), 512, 0, stream>>>(
            hin, (t == 0) ? Wc0 : Wc, BATCH_N, K4, H_DIM,
            nullptr, nullptr, biasc, hout, hr_t);
        if (!batched) {
            gemm256<false><<<(BATCH_N / 256) * (H_DIM / 256), 512, 0, stream>>>(
                hr_t, Wob, BATCH_N, H_DIM, H_DIM,
                out + (size_t)t * hr_step, bout, nullptr, nullptr, nullptr);
        }
    }
    if (batched) {
        // one big out GEMM: M = 16*4096, N = 1024, K = 1024
        gemm256<false><<<((NSTEPS * BATCH_N) / 256) * (H_DIM / 256), 512, 0, stream>>>(
            hr_all, Wob, NSTEPS * BATCH_N, H_DIM, H_DIM,
            out, bout, nullptr, nullptr, nullptr);
    }
}